// Round 1
// 535.684 us; speedup vs baseline: 1.0808x; 1.0808x over previous
//
#include <hip/hip_runtime.h>
#include <cstdint>
#include <cstddef>

// Problem constants
#define TOKENS 2048
#define DM 1024
#define DFF 2048
#define HC 4096   // 2*DFF
#define NE 16
#define BM 256    // M-tile: one tile covers any typical expert (cnt ~ 128 +/- 11)

typedef __bf16 bf16x8 __attribute__((ext_vector_type(8)));
typedef float floatx4 __attribute__((ext_vector_type(4)));

static __device__ __forceinline__ unsigned short f2bf(float f) {
    union { float f; unsigned int u; } v; v.f = f;
    unsigned int r = v.u + 0x7fffu + ((v.u >> 16) & 1u);  // RNE
    return (unsigned short)(r >> 16);
}

// lgkm-only barrier: does NOT drain vmcnt, so register-destined global loads
// (the weight prefetch) stay in flight across the workgroup barrier.
// __syncthreads() would emit s_waitcnt vmcnt(0) and serialize every K-step.
static __device__ __forceinline__ void lds_barrier() {
    asm volatile("s_waitcnt lgkmcnt(0)" ::: "memory");
    __builtin_amdgcn_s_barrier();
    __builtin_amdgcn_sched_barrier(0);
}

// ---------------- gating: logits (fp64 accum), softmax, argmax — NO atomics --
__global__ __launch_bounds__(256) void moe_gating(
    const float* __restrict__ x, const float* __restrict__ Wga, const float* __restrict__ bga,
    const float* __restrict__ Wgb, const float* __restrict__ bgb,
    float* __restrict__ probsA, float* __restrict__ probsB, int* __restrict__ e_idx)
{
    int wv = threadIdx.x >> 6, lane = threadIdx.x & 63;
    int t = blockIdx.x * 4 + wv;
    const float* xr = x + (size_t)t * DM;
    double aA[4] = {0.,0.,0.,0.}, aB[4] = {0.,0.,0.,0.};
    for (int k = lane; k < DM; k += 64) {
        double xv = (double)xr[k];
        float4 wa = *(const float4*)(Wga + k * 4);
        float4 wb = *(const float4*)(Wgb + k * 4);
        aA[0] += xv * wa.x; aA[1] += xv * wa.y; aA[2] += xv * wa.z; aA[3] += xv * wa.w;
        aB[0] += xv * wb.x; aB[1] += xv * wb.y; aB[2] += xv * wb.z; aB[3] += xv * wb.w;
    }
    #pragma unroll
    for (int off = 32; off >= 1; off >>= 1) {
        #pragma unroll
        for (int j = 0; j < 4; ++j) {
            aA[j] += __shfl_xor(aA[j], off);
            aB[j] += __shfl_xor(aB[j], off);
        }
    }
    if (lane == 0) {
        double lA[4], lB[4];
        #pragma unroll
        for (int j = 0; j < 4; ++j) {
            lA[j] = aA[j] + (double)bga[j];
            lB[j] = aB[j] + (double)bgb[j];
        }
        int ia = 0, ib = 0;
        #pragma unroll
        for (int j = 1; j < 4; ++j) {
            if (lA[j] > lA[ia]) ia = j;   // first-max, matches np.argmax
            if (lB[j] > lB[ib]) ib = j;
        }
        double sA = 0., sB = 0., pA[4], pB[4];
        #pragma unroll
        for (int j = 0; j < 4; ++j) {
            pA[j] = exp(lA[j] - lA[ia]); sA += pA[j];
            pB[j] = exp(lB[j] - lB[ib]); sB += pB[j];
        }
        float4 oa, ob;
        oa.x = (float)(pA[0]/sA); oa.y = (float)(pA[1]/sA);
        oa.z = (float)(pA[2]/sA); oa.w = (float)(pA[3]/sA);
        ob.x = (float)(pB[0]/sB); ob.y = (float)(pB[1]/sB);
        ob.z = (float)(pB[2]/sB); ob.w = (float)(pB[3]/sB);
        *(float4*)(probsA + t * 4) = oa;
        *(float4*)(probsB + t * 4) = ob;
        e_idx[t] = ia * 4 + ib;
    }
}

// ---------------- single-block stats: sums, counts, offsets, aux ------------
__global__ __launch_bounds__(256) void moe_stats(
    const float* __restrict__ probsA, const float* __restrict__ probsB,
    const int* __restrict__ e_idx,
    int* __restrict__ countE, int* __restrict__ offsets, float* __restrict__ aux_out)
{
    __shared__ float sA[4], sB[4];
    __shared__ int cA[4], cB[4], cE[16];
    int tid = threadIdx.x;
    if (tid < 4) { sA[tid] = 0.f; sB[tid] = 0.f; cA[tid] = 0; cB[tid] = 0; }
    if (tid < 16) cE[tid] = 0;
    __syncthreads();
    float lA[4] = {0,0,0,0}, lB[4] = {0,0,0,0};
    for (int t = tid; t < TOKENS; t += 256) {
        float4 pa = *(const float4*)(probsA + t * 4);
        float4 pb = *(const float4*)(probsB + t * 4);
        lA[0] += pa.x; lA[1] += pa.y; lA[2] += pa.z; lA[3] += pa.w;
        lB[0] += pb.x; lB[1] += pb.y; lB[2] += pb.z; lB[3] += pb.w;
        int e = e_idx[t];
        atomicAdd(&cE[e], 1);
        atomicAdd(&cA[e >> 2], 1);
        atomicAdd(&cB[e & 3], 1);
    }
    #pragma unroll
    for (int j = 0; j < 4; ++j) {
        atomicAdd(&sA[j], lA[j]);
        atomicAdd(&sB[j], lB[j]);
    }
    __syncthreads();
    if (tid == 0) {
        int acc = 0;
        for (int e = 0; e < NE; ++e) { offsets[e] = acc; countE[e] = cE[e]; acc += cE[e]; }
        offsets[NE] = acc;
        float invT = 1.0f / (float)TOKENS;
        float auxA = 0.f, auxB = 0.f;
        for (int j = 0; j < 4; ++j) {
            auxA += (sA[j] * invT) * ((float)cA[j] * invT);
            auxB += (sB[j] * invT) * ((float)cB[j] * invT);
        }
        aux_out[0] = 4.0f * auxA + 4.0f * auxB;
    }
}

// ---------------- assign each token a compact slot within its expert --------
__global__ __launch_bounds__(256) void moe_slot(const int* __restrict__ e_idx,
                                                const int* __restrict__ offsets,
                                                int* __restrict__ cursor, int* __restrict__ perm)
{
    int t = blockIdx.x * 256 + threadIdx.x;
    int e = e_idx[t];
    int s = offsets[e] + atomicAdd(&cursor[e], 1);
    perm[s] = t;
}

// ---------------- gather x rows into expert-sorted bf16 buffer --------------
__global__ __launch_bounds__(256) void moe_gather(const float* __restrict__ x,
                                                  const int* __restrict__ perm,
                                                  unsigned short* __restrict__ Xg)
{
    int s = blockIdx.x;
    int t = perm[s];
    int i = threadIdx.x * 4;
    float4 v = *(const float4*)(x + (size_t)t * DM + i);
    ushort4 o;
    o.x = f2bf(v.x); o.y = f2bf(v.y); o.z = f2bf(v.z); o.w = f2bf(v.w);
    *(ushort4*)(Xg + (size_t)s * DM + i) = o;
}

// ---------------- GEMM1: h = Xg @ W1[e] (+b1), act = a * silu(g) ------------
// grid (DFF/64, NE). block 512 = 8 waves in a 2(M)x4(N) grid; BM=256 so one
// M-tile covers a typical expert (no weight panel re-read). Per wave: 8
// m-frags x 16 a-cols + 16 g-cols, identical math to the old 128-tile.
// B-frags loaded direct from global fp32 one K-step ahead; the lgkm-only
// barrier keeps those loads in flight across the step boundary (the old
// __syncthreads drained vmcnt(0) every step and exposed full HBM latency).
__global__ __launch_bounds__(512) void moe_ffn1(
    const unsigned short* __restrict__ Xg, const float* __restrict__ W1,
    const float* __restrict__ b1, const int* __restrict__ countE,
    const int* __restrict__ offsets, unsigned short* __restrict__ actbuf)
{
    int e = blockIdx.y;
    int cnt = countE[e];
    if (cnt == 0) return;
    int base = offsets[e];
    int n0 = blockIdx.x * 64;
    __shared__ __align__(16) unsigned short Xs[2 * BM * 40];
    int tid = threadIdx.x, wv = tid >> 6, lane = tid & 63;
    int quad = lane >> 4, l15 = lane & 15;
    int wvM = wv >> 2, wvN = wv & 3;
    const float* W1e = W1 + (size_t)e * DM * HC;
    int col = n0 + wvN * 16 + l15;
    const float* pa = W1e + col;
    const float* pg = W1e + DFF + col;
    float ba = b1[e * HC + col];
    float bg = b1[e * HC + DFF + col];
    int row = tid >> 2, kc = tid & 3;   // staging: 128 rows/pass, 2 passes

    for (int m0 = 0; m0 < cnt; m0 += BM) {
        floatx4 acc[8][2];
        #pragma unroll
        for (int i = 0; i < 8; ++i) {
            acc[i][0] = floatx4{0.f,0.f,0.f,0.f};
            acc[i][1] = floatx4{0.f,0.f,0.f,0.f};
        }
        // prologue: stage k-step 0 into buffer 0, load B-frags for step 0
        {
            uint4 av0 = {0u,0u,0u,0u}, av1 = {0u,0u,0u,0u};
            int ma = m0 + row, mb = m0 + row + 128;
            if (ma < cnt) av0 = *(const uint4*)(Xg + (size_t)(base + ma) * DM + kc * 8);
            if (mb < cnt) av1 = *(const uint4*)(Xg + (size_t)(base + mb) * DM + kc * 8);
            *(uint4*)(Xs + row * 40 + kc * 8) = av0;
            *(uint4*)(Xs + (row + 128) * 40 + kc * 8) = av1;
        }
        float curA[8], curG[8], nxtA[8], nxtG[8];
        {
            const float* qa = pa + (size_t)(quad * 8) * HC;
            const float* qg = pg + (size_t)(quad * 8) * HC;
            #pragma unroll
            for (int j = 0; j < 8; ++j) { curA[j] = qa[(size_t)j * HC]; curG[j] = qg[(size_t)j * HC]; }
        }
        lds_barrier();
        for (int ks = 0; ks < DM / 32; ++ks) {
            int buf = ks & 1;
            uint4 nv0 = {0u,0u,0u,0u}, nv1 = {0u,0u,0u,0u};
            bool more = (ks + 1 < DM / 32);
            if (more) {
                // issue A-tile loads FIRST (oldest), then B prefetch, so the
                // ds_write's auto vmcnt wait leaves the B loads outstanding.
                int k0n = (ks + 1) * 32;
                int ma = m0 + row, mb = m0 + row + 128;
                if (ma < cnt) nv0 = *(const uint4*)(Xg + (size_t)(base + ma) * DM + k0n + kc * 8);
                if (mb < cnt) nv1 = *(const uint4*)(Xg + (size_t)(base + mb) * DM + k0n + kc * 8);
                const float* qa = pa + (size_t)((ks + 1) * 32 + quad * 8) * HC;
                const float* qg = pg + (size_t)((ks + 1) * 32 + quad * 8) * HC;
                #pragma unroll
                for (int j = 0; j < 8; ++j) { nxtA[j] = qa[(size_t)j * HC]; nxtG[j] = qg[(size_t)j * HC]; }
            }
            bf16x8 af[8];
            #pragma unroll
            for (int i = 0; i < 8; ++i)
                af[i] = *(const bf16x8*)(Xs + buf * (BM * 40) + (wvM * 128 + i * 16 + l15) * 40 + quad * 8);
            bf16x8 fa, fg;
            #pragma unroll
            for (int j = 0; j < 8; ++j) { fa[j] = (__bf16)curA[j]; fg[j] = (__bf16)curG[j]; }
            #pragma unroll
            for (int i = 0; i < 8; ++i) {
                acc[i][0] = __builtin_amdgcn_mfma_f32_16x16x32_bf16(af[i], fa, acc[i][0], 0, 0, 0);
                acc[i][1] = __builtin_amdgcn_mfma_f32_16x16x32_bf16(af[i], fg, acc[i][1], 0, 0, 0);
            }
            if (more) {
                *(uint4*)(Xs + (buf ^ 1) * (BM * 40) + row * 40 + kc * 8) = nv0;
                *(uint4*)(Xs + (buf ^ 1) * (BM * 40) + (row + 128) * 40 + kc * 8) = nv1;
                #pragma unroll
                for (int j = 0; j < 8; ++j) { curA[j] = nxtA[j]; curG[j] = nxtG[j]; }
            }
            lds_barrier();
        }
        #pragma unroll
        for (int i = 0; i < 8; ++i) {
            #pragma unroll
            for (int r = 0; r < 4; ++r) {
                int mr = m0 + wvM * 128 + i * 16 + quad * 4 + r;
                if (mr < cnt) {
                    float a = acc[i][0][r] + ba;
                    float g = acc[i][1][r] + bg;
                    float sg = 1.0f / (1.0f + __expf(-g));
                    actbuf[(size_t)(base + mr) * DFF + col] = f2bf(a * (g * sg));
                }
            }
        }
    }
}

// ---------------- GEMM2: y = act @ W2[e] + b2, scatter rows via perm --------
// grid (DM/64, NE). Same 8-wave BM=256 structure.
__global__ __launch_bounds__(512) void moe_ffn2(
    const unsigned short* __restrict__ actbuf, const float* __restrict__ W2,
    const float* __restrict__ b2, const int* __restrict__ countE,
    const int* __restrict__ offsets, const int* __restrict__ perm,
    float* __restrict__ out)
{
    int e = blockIdx.y;
    int cnt = countE[e];
    if (cnt == 0) return;
    int base = offsets[e];
    int n0 = blockIdx.x * 64;
    __shared__ __align__(16) unsigned short As[2 * BM * 40];
    int tid = threadIdx.x, wv = tid >> 6, lane = tid & 63;
    int quad = lane >> 4, l15 = lane & 15;
    int wvM = wv >> 2, wvN = wv & 3;
    const float* W2e = W2 + (size_t)e * DFF * DM;
    int col = n0 + wvN * 16 + l15;
    const float* pb = W2e + col;
    float bias = b2[e * DM + col];
    int row = tid >> 2, kc = tid & 3;

    for (int m0 = 0; m0 < cnt; m0 += BM) {
        floatx4 acc[8];
        #pragma unroll
        for (int i = 0; i < 8; ++i) acc[i] = floatx4{0.f,0.f,0.f,0.f};
        {
            uint4 av0 = {0u,0u,0u,0u}, av1 = {0u,0u,0u,0u};
            int ma = m0 + row, mb = m0 + row + 128;
            if (ma < cnt) av0 = *(const uint4*)(actbuf + (size_t)(base + ma) * DFF + kc * 8);
            if (mb < cnt) av1 = *(const uint4*)(actbuf + (size_t)(base + mb) * DFF + kc * 8);
            *(uint4*)(As + row * 40 + kc * 8) = av0;
            *(uint4*)(As + (row + 128) * 40 + kc * 8) = av1;
        }
        float curB[8], nxtB[8];
        {
            const float* qb = pb + (size_t)(quad * 8) * DM;
            #pragma unroll
            for (int j = 0; j < 8; ++j) curB[j] = qb[(size_t)j * DM];
        }
        lds_barrier();
        for (int ks = 0; ks < DFF / 32; ++ks) {
            int buf = ks & 1;
            uint4 nv0 = {0u,0u,0u,0u}, nv1 = {0u,0u,0u,0u};
            bool more = (ks + 1 < DFF / 32);
            if (more) {
                int k0n = (ks + 1) * 32;
                int ma = m0 + row, mb = m0 + row + 128;
                if (ma < cnt) nv0 = *(const uint4*)(actbuf + (size_t)(base + ma) * DFF + k0n + kc * 8);
                if (mb < cnt) nv1 = *(const uint4*)(actbuf + (size_t)(base + mb) * DFF + k0n + kc * 8);
                const float* qb = pb + (size_t)((ks + 1) * 32 + quad * 8) * DM;
                #pragma unroll
                for (int j = 0; j < 8; ++j) nxtB[j] = qb[(size_t)j * DM];
            }
            bf16x8 af[8];
            #pragma unroll
            for (int i = 0; i < 8; ++i)
                af[i] = *(const bf16x8*)(As + buf * (BM * 40) + (wvM * 128 + i * 16 + l15) * 40 + quad * 8);
            bf16x8 fb;
            #pragma unroll
            for (int j = 0; j < 8; ++j) fb[j] = (__bf16)curB[j];
            #pragma unroll
            for (int i = 0; i < 8; ++i)
                acc[i] = __builtin_amdgcn_mfma_f32_16x16x32_bf16(af[i], fb, acc[i], 0, 0, 0);
            if (more) {
                *(uint4*)(As + (buf ^ 1) * (BM * 40) + row * 40 + kc * 8) = nv0;
                *(uint4*)(As + (buf ^ 1) * (BM * 40) + (row + 128) * 40 + kc * 8) = nv1;
                #pragma unroll
                for (int j = 0; j < 8; ++j) curB[j] = nxtB[j];
            }
            lds_barrier();
        }
        #pragma unroll
        for (int i = 0; i < 8; ++i) {
            #pragma unroll
            for (int r = 0; r < 4; ++r) {
                int mr = m0 + wvM * 128 + i * 16 + quad * 4 + r;
                if (mr < cnt) {
                    int t = perm[base + mr];
                    out[(size_t)t * DM + col] = acc[i][r] + bias;
                }
            }
        }
    }
}

extern "C" void kernel_launch(void* const* d_in, const int* in_sizes, int n_in,
                              void* d_out, int out_size, void* d_ws, size_t ws_size,
                              hipStream_t stream)
{
    (void)in_sizes; (void)n_in; (void)out_size; (void)ws_size;
    const float* x   = (const float*)d_in[0];
    const float* W1  = (const float*)d_in[1];
    const float* b1  = (const float*)d_in[2];
    const float* W2  = (const float*)d_in[3];
    const float* b2  = (const float*)d_in[4];
    const float* Wga = (const float*)d_in[5];
    const float* bga = (const float*)d_in[6];
    const float* Wgb = (const float*)d_in[7];
    const float* bgb = (const float*)d_in[8];
    float* out = (float*)d_out;

    // workspace layout (16 MiB):
    //   0      countE[16]     64    cursor[16]     256  offsets[17]
    //   512    e_idx[2048]    8704  perm[2048]
    //   16896  probsA[8192]f  49664 probsB[8192]f
    //   131072 Xg bf16[2048*1024] (4 MiB)
    //   8 MiB  actbuf bf16[2048*2048] (8 MiB)
    char* ws = (char*)d_ws;
    int*   countE  = (int*)(ws + 0);
    int*   cursor  = (int*)(ws + 64);
    int*   offsets = (int*)(ws + 256);
    int*   e_idx   = (int*)(ws + 512);
    int*   perm    = (int*)(ws + 8704);
    float* probsA  = (float*)(ws + 16896);
    float* probsB  = (float*)(ws + 49664);
    unsigned short* Xg     = (unsigned short*)(ws + 131072);
    unsigned short* actbuf = (unsigned short*)(ws + (size_t)8 * 1024 * 1024);

    hipMemsetAsync(ws, 0, 256, stream);   // cursor (and countE, harmlessly)
    moe_gating<<<TOKENS / 4, 256, 0, stream>>>(x, Wga, bga, Wgb, bgb,
                                               probsA, probsB, e_idx);
    moe_stats<<<1, 256, 0, stream>>>(probsA, probsB, e_idx, countE, offsets,
                                     out + (size_t)TOKENS * DM);
    moe_slot<<<TOKENS / 256, 256, 0, stream>>>(e_idx, offsets, cursor, perm);
    moe_gather<<<TOKENS, 256, 0, stream>>>(x, perm, Xg);
    moe_ffn1<<<dim3(DFF / 64, NE), 512, 0, stream>>>(Xg, W1, b1, countE, offsets, actbuf);
    moe_ffn2<<<dim3(DM / 64, NE), 512, 0, stream>>>(actbuf, W2, b2, countE, offsets, perm, out);
}